// Round 2
// baseline (369.180 us; speedup 1.0000x reference)
//
#include <hip/hip_runtime.h>
#include <hip/hip_bf16.h>

#define BT 4
#define TT 4096
#define DM 1024
#define DH 64
#define NRE 17  // 2*MAX_REL+1

using bf16 = __hip_bfloat16;
typedef __attribute__((ext_vector_type(8))) short short8;
typedef __attribute__((ext_vector_type(4))) float float4v;

static __device__ __forceinline__ short8 load8(const bf16* p) {
    return *reinterpret_cast<const short8*>(p);
}

static __device__ __forceinline__ short bfbits(float x) {
    return (short)__bfloat16_as_ushort(__float2bfloat16(x));
}

// load 8 consecutive floats, convert to 8 bf16 (A/B fragment for 16x16x32)
static __device__ __forceinline__ short8 cvt8(const float* p) {
    float4v a = *reinterpret_cast<const float4v*>(p);
    float4v b = *reinterpret_cast<const float4v*>(p + 4);
    short8 r;
    r[0] = bfbits(a[0]); r[1] = bfbits(a[1]); r[2] = bfbits(a[2]); r[3] = bfbits(a[3]);
    r[4] = bfbits(b[0]); r[5] = bfbits(b[1]); r[6] = bfbits(b[2]); r[7] = bfbits(b[3]);
    return r;
}

// ---------------------------------------------------------------------------
// Kernel 1: fused QKV projection.  x[16384,1024] f32 @ W^T (f32) -> Q,K
// [16384,64] bf16 row-major, V transposed Vt[b][64][4096] bf16.
// Block = 256 thr (4 waves); block does 64 rows; wave w = M-tile w (16 rows)
// x all 12 N-tiles (Q:0-3, K:4-7, V:8-11).  K-loop over DM in steps of 32.
// ---------------------------------------------------------------------------
__global__ __launch_bounds__(256) void qkv_proj(
    const float* __restrict__ x,
    const float* __restrict__ Wq, const float* __restrict__ Wk,
    const float* __restrict__ Wv,
    bf16* __restrict__ Qb, bf16* __restrict__ Kb, bf16* __restrict__ Vt)
{
    const int w    = threadIdx.x >> 6;
    const int lane = threadIdx.x & 63;
    const int quad = lane >> 4;
    const int l16  = lane & 15;
    const int row0 = blockIdx.x * 64;
    const int arow = row0 + 16 * w + l16;

    const float* Ws[3] = {Wq, Wk, Wv};

    float4v acc[12];
#pragma unroll
    for (int i = 0; i < 12; i++) acc[i] = (float4v)(0.f);

    for (int k0 = 0; k0 < DM; k0 += 32) {
        short8 a = cvt8(&x[(size_t)arow * DM + k0 + quad * 8]);
#pragma unroll
        for (int nt = 0; nt < 12; nt++) {
            const float* Wp = Ws[nt >> 2];
            const int rw = (nt & 3) * 16 + l16;
            short8 b = cvt8(&Wp[(size_t)rw * DM + k0 + quad * 8]);
            acc[nt] = __builtin_amdgcn_mfma_f32_16x16x32_bf16(a, b, acc[nt], 0, 0, 0);
        }
    }

#pragma unroll
    for (int nt = 0; nt < 12; nt++) {
#pragma unroll
        for (int r = 0; r < 4; r++) {
            const int i = row0 + 16 * w + quad * 4 + r;   // global row (b*T+t)
            const int c = 16 * nt + l16;                  // 0..191
            bf16 hv = __float2bfloat16(acc[nt][r]);
            if (c < 64) {
                Qb[(size_t)i * DH + c] = hv;
            } else if (c < 128) {
                Kb[(size_t)i * DH + (c - 64)] = hv;
            } else {
                const int d = c - 128;
                const int b_ = i >> 12;        // /4096
                const int t  = i & (TT - 1);
                Vt[((size_t)b_ * DH + d) * TT + t] = hv;
            }
        }
    }
}

// ---------------------------------------------------------------------------
// Kernel 2: flash causal attention with clipped relative bias.
// Q_TILE=32 (2 waves, wave = 16 q-rows), KV_TILE=64.  Grid 512:
// batch = idx&3, t = idx>>2  =>  CU c gets tiles t and t+64 (balanced).
// S in C-layout (col=lane&15, row=quad*4+reg); P round-trips LDS (stride 72,
// rows wave-private so in-wave lgkmcnt ordering suffices) into A-operand
// layout (m=lane&15, k=quad*8+j).
// ---------------------------------------------------------------------------
__global__ __launch_bounds__(128) void attn(
    const bf16* __restrict__ Qb, const bf16* __restrict__ Kb,
    const bf16* __restrict__ Vt, const float* __restrict__ rel,
    float* __restrict__ out)
{
    __shared__ float s_rel[NRE];
    __shared__ __align__(16) bf16 Pls[32 * 72];  // pad 64->72: 2-way (free) banks

    const int w     = threadIdx.x >> 6;
    const int lane  = threadIdx.x & 63;
    const int quad  = lane >> 4;
    const int l16   = lane & 15;
    const int batch = blockIdx.x & 3;
    const int t     = blockIdx.x >> 2;
    const int q0    = t * 32;

    if (threadIdx.x < NRE) s_rel[threadIdx.x] = rel[threadIdx.x];
    __syncthreads();
    const float rel0 = s_rel[0];

    const size_t bbase = (size_t)batch * TT;

    // Q A-fragments (persist whole kernel)
    short8 aq0, aq1;
    {
        const bf16* qp = &Qb[(bbase + q0 + 16 * w + l16) * DH];
        aq0 = load8(qp + quad * 8);
        aq1 = load8(qp + 32 + quad * 8);
    }

    float4v o[4];
    float m_st[4], l_st[4];
#pragma unroll
    for (int nt = 0; nt < 4; nt++) o[nt] = (float4v)(0.f);
#pragma unroll
    for (int r = 0; r < 4; r++) { m_st[r] = -1e30f; l_st[r] = 0.f; }

    const int i_base = q0 + 16 * w + quad * 4;

    for (int j0 = 0; j0 < q0 + 32; j0 += 64) {
        // ---- S = Q K^T ----
        float4v s[4];
#pragma unroll
        for (int nt = 0; nt < 4; nt++) s[nt] = (float4v)(0.f);
#pragma unroll
        for (int nt = 0; nt < 4; nt++) {
            const bf16* kp = &Kb[(bbase + j0 + 16 * nt + l16) * DH];
            short8 b0 = load8(kp + quad * 8);
            short8 b1 = load8(kp + 32 + quad * 8);
            s[nt] = __builtin_amdgcn_mfma_f32_16x16x32_bf16(aq0, b0, s[nt], 0, 0, 0);
            s[nt] = __builtin_amdgcn_mfma_f32_16x16x32_bf16(aq1, b1, s[nt], 0, 0, 0);
        }

        // ---- scale + bias + causal mask ----
        float p[4][4];
        float mcur[4];
#pragma unroll
        for (int r = 0; r < 4; r++) mcur[r] = -1e30f;

        if (j0 + 71 <= q0) {
            // interior tile: all deltas <= -8, no mask, bias = rel[0]
#pragma unroll
            for (int nt = 0; nt < 4; nt++)
#pragma unroll
                for (int r = 0; r < 4; r++) {
                    float val = s[nt][r] * 0.125f + rel0;
                    p[nt][r] = val;
                    mcur[r] = fmaxf(mcur[r], val);
                }
        } else {
#pragma unroll
            for (int nt = 0; nt < 4; nt++) {
                const int j = j0 + 16 * nt + l16;
#pragma unroll
                for (int r = 0; r < 4; r++) {
                    const int i = i_base + r;
                    const int d = j - i;
                    int idx = d + 8;
                    idx = idx < 0 ? 0 : (idx > 16 ? 16 : idx);
                    float val = s[nt][r] * 0.125f + s_rel[idx];
                    val = (d > 0) ? -1e30f : val;
                    p[nt][r] = val;
                    mcur[r] = fmaxf(mcur[r], val);
                }
            }
        }

        // ---- row max across the 16 lanes of each quad-group ----
#pragma unroll
        for (int m = 1; m < 16; m <<= 1)
#pragma unroll
            for (int r = 0; r < 4; r++)
                mcur[r] = fmaxf(mcur[r], __shfl_xor(mcur[r], m, 64));

        float alpha[4], lsum[4];
#pragma unroll
        for (int r = 0; r < 4; r++) {
            const float mn = fmaxf(m_st[r], mcur[r]);
            alpha[r] = __expf(m_st[r] - mn);
            m_st[r] = mn;
            lsum[r] = 0.f;
        }
#pragma unroll
        for (int nt = 0; nt < 4; nt++)
#pragma unroll
            for (int r = 0; r < 4; r++) {
                const float pv = __expf(p[nt][r] - m_st[r]);
                p[nt][r] = pv;
                lsum[r] += pv;
            }
#pragma unroll
        for (int m = 1; m < 16; m <<= 1)
#pragma unroll
            for (int r = 0; r < 4; r++)
                lsum[r] += __shfl_xor(lsum[r], m, 64);
#pragma unroll
        for (int r = 0; r < 4; r++)
            l_st[r] = l_st[r] * alpha[r] + lsum[r];
#pragma unroll
        for (int nt = 0; nt < 4; nt++)
#pragma unroll
            for (int r = 0; r < 4; r++) o[nt][r] *= alpha[r];

        // ---- P (C-layout) -> LDS -> A-operand layout; rows are wave-private
        //      so in-wave lgkmcnt ordering suffices (no barrier needed). ----
#pragma unroll
        for (int nt = 0; nt < 4; nt++)
#pragma unroll
            for (int r = 0; r < 4; r++)
                Pls[(16 * w + quad * 4 + r) * 72 + 16 * nt + l16] =
                    __float2bfloat16(p[nt][r]);

        short8 ap0 = load8(&Pls[(16 * w + l16) * 72 + quad * 8]);
        short8 ap1 = load8(&Pls[(16 * w + l16) * 72 + 32 + quad * 8]);

        // ---- O += P V  (Vt gives contiguous 16B B-operand loads) ----
#pragma unroll
        for (int nt = 0; nt < 4; nt++) {
            const bf16* vp = &Vt[((size_t)batch * DH + 16 * nt + l16) * TT + j0];
            short8 bv0 = load8(vp + quad * 8);
            short8 bv1 = load8(vp + 32 + quad * 8);
            o[nt] = __builtin_amdgcn_mfma_f32_16x16x32_bf16(ap0, bv0, o[nt], 0, 0, 0);
            o[nt] = __builtin_amdgcn_mfma_f32_16x16x32_bf16(ap1, bv1, o[nt], 0, 0, 0);
        }
    }

    // ---- epilogue: O / l  (f32 output) ----
#pragma unroll
    for (int nt = 0; nt < 4; nt++)
#pragma unroll
        for (int r = 0; r < 4; r++) {
            const int i = i_base + r;
            out[(bbase + i) * DH + 16 * nt + l16] = o[nt][r] / l_st[r];
        }
}

// ---------------------------------------------------------------------------
extern "C" void kernel_launch(void* const* d_in, const int* in_sizes, int n_in,
                              void* d_out, int out_size, void* d_ws, size_t ws_size,
                              hipStream_t stream)
{
    const float* x   = (const float*)d_in[0];
    const float* Wq  = (const float*)d_in[1];
    const float* Wk  = (const float*)d_in[2];
    const float* Wv  = (const float*)d_in[3];
    const float* rel = (const float*)d_in[4];
    float* out = (float*)d_out;

    bf16* Qb = (bf16*)d_ws;                       // [B*T, 64] bf16
    bf16* Kb = Qb + (size_t)BT * TT * DH;         // [B*T, 64] bf16
    bf16* Vt = Kb + (size_t)BT * TT * DH;         // [B, 64, T] bf16

    qkv_proj<<<256, 256, 0, stream>>>(x, Wq, Wk, Wv, Qb, Kb, Vt);
    attn<<<512, 128, 0, stream>>>(Qb, Kb, Vt, rel, out);
}

// Round 3
// 266.327 us; speedup vs baseline: 1.3862x; 1.3862x over previous
//
#include <hip/hip_runtime.h>
#include <hip/hip_bf16.h>

#define BT 4
#define TT 4096
#define DM 1024
#define DH 64
#define NRE 17  // 2*MAX_REL+1

using bf16 = __hip_bfloat16;
typedef __attribute__((ext_vector_type(8))) short short8;
typedef __attribute__((ext_vector_type(4))) short short4v;
typedef __attribute__((ext_vector_type(4))) float float4v;

static __device__ __forceinline__ short8 load8(const bf16* p) {
    return *reinterpret_cast<const short8*>(p);
}
static __device__ __forceinline__ short bfbits(float x) {
    return (short)__bfloat16_as_ushort(__float2bfloat16(x));
}
// load 8 consecutive floats, convert to 8 bf16 (A/B fragment for 16x16x32)
static __device__ __forceinline__ short8 cvt8(const float* p) {
    float4v a = *reinterpret_cast<const float4v*>(p);
    float4v b = *reinterpret_cast<const float4v*>(p + 4);
    short8 r;
    r[0] = bfbits(a[0]); r[1] = bfbits(a[1]); r[2] = bfbits(a[2]); r[3] = bfbits(a[3]);
    r[4] = bfbits(b[0]); r[5] = bfbits(b[1]); r[6] = bfbits(b[2]); r[7] = bfbits(b[3]);
    return r;
}

// ---------------------------------------------------------------------------
// Kernel 0: W prep. Concatenate Wq|Wk|Wv rows (192 x 1024) and convert to
// bf16 once, so the GEMM reads half the W bytes with no cvt on the B-path.
// ---------------------------------------------------------------------------
__global__ __launch_bounds__(256) void w_prep(
    const float* __restrict__ Wq, const float* __restrict__ Wk,
    const float* __restrict__ Wv, bf16* __restrict__ Wb)
{
    const int row = blockIdx.x;          // 0..191
    const float* src = (row < 64) ? &Wq[(size_t)row * DM]
                     : (row < 128) ? &Wk[(size_t)(row - 64) * DM]
                                   : &Wv[(size_t)(row - 128) * DM];
    float4v v = reinterpret_cast<const float4v*>(src)[threadIdx.x];
    short4v s;
    s[0] = bfbits(v[0]); s[1] = bfbits(v[1]); s[2] = bfbits(v[2]); s[3] = bfbits(v[3]);
    *reinterpret_cast<short4v*>(&Wb[(size_t)row * DM + 4 * threadIdx.x]) = s;
}

// ---------------------------------------------------------------------------
// Kernel 1: QKV GEMM. x[16384,1024] f32 @ Wb^T(bf16) -> Q,K [16384,64] bf16,
// V transposed Vt[b][64][4096] bf16.
// 1024 blocks x 4 waves (16 waves/CU). Block = 16 rows; wave w = cols
// [48w, 48w+48) (3 N-tiles). Per k-step: 1 A-load(+cvt) + 3 B-loads + 3 MFMA.
// ---------------------------------------------------------------------------
__global__ __launch_bounds__(256) void qkv_gemm(
    const float* __restrict__ x, const bf16* __restrict__ Wb,
    bf16* __restrict__ Qb, bf16* __restrict__ Kb, bf16* __restrict__ Vt)
{
    const int w    = threadIdx.x >> 6;
    const int lane = threadIdx.x & 63;
    const int quad = lane >> 4;
    const int l16  = lane & 15;
    const int row0 = blockIdx.x * 16;
    const int arow = row0 + l16;

    const bf16* Wbase = Wb + (size_t)(48 * w) * DM;

    float4v acc[3];
#pragma unroll
    for (int i = 0; i < 3; i++) acc[i] = (float4v)(0.f);

    for (int k0 = 0; k0 < DM; k0 += 32) {
        short8 a = cvt8(&x[(size_t)arow * DM + k0 + quad * 8]);
#pragma unroll
        for (int nt = 0; nt < 3; nt++) {
            short8 b = load8(&Wbase[(size_t)(16 * nt + l16) * DM + k0 + quad * 8]);
            acc[nt] = __builtin_amdgcn_mfma_f32_16x16x32_bf16(a, b, acc[nt], 0, 0, 0);
        }
    }

#pragma unroll
    for (int nt = 0; nt < 3; nt++) {
        const int c = 48 * w + 16 * nt + l16;   // 0..191
#pragma unroll
        for (int r = 0; r < 4; r++) {
            const int i = row0 + quad * 4 + r;  // global row (b*T+t)
            bf16 hv = __float2bfloat16(acc[nt][r]);
            if (c < 64) {
                Qb[(size_t)i * DH + c] = hv;
            } else if (c < 128) {
                Kb[(size_t)i * DH + (c - 64)] = hv;
            } else {
                const int d = c - 128;
                const int b_ = i >> 12;        // /4096
                const int t  = i & (TT - 1);
                Vt[((size_t)b_ * DH + d) * TT + t] = hv;
            }
        }
    }
}

// ---------------------------------------------------------------------------
// Kernel 2: flash causal attention, KV split 4-ways inside the block.
// Block = 512 thr (8 waves): wave w -> row-half (w&1, 16 q-rows) x KV stream
// (w>>1 of 4).  Per-stream partials (m,l,O) merged through LDS at the end.
// Grid 512: batch = idx&3; q-tile remapped big/small pairs for balance.
// ---------------------------------------------------------------------------
__global__ __launch_bounds__(512) void attn(
    const bf16* __restrict__ Qb, const bf16* __restrict__ Kb,
    const bf16* __restrict__ Vt, const float* __restrict__ rel,
    float* __restrict__ out)
{
    __shared__ float s_rel[NRE];
    __shared__ __align__(16) bf16 Pls[8][16 * 72]; // per-wave P staging
    __shared__ float m_sh[4][32], l_sh[4][32];
    __shared__ float O_sh[4][32][64];

    const int w     = threadIdx.x >> 6;
    const int lane  = threadIdx.x & 63;
    const int quad  = lane >> 4;
    const int l16   = lane & 15;
    const int half  = w & 1;     // which 16 q-rows
    const int strm  = w >> 1;    // KV stream 0..3
    const int batch = blockIdx.x & 3;
    const int b2    = blockIdx.x >> 2;                     // 0..127
    const int t     = (b2 & 1) ? (127 - (b2 >> 1)) : (b2 >> 1);
    const int q0    = t * 32;

    if (threadIdx.x < NRE) s_rel[threadIdx.x] = rel[threadIdx.x];
    __syncthreads();
    const float rel0 = s_rel[0];

    const size_t bbase = (size_t)batch * TT;
    bf16* Pw = &Pls[w][0];

    // Q A-fragments for this wave's 16 rows
    short8 aq0, aq1;
    {
        const bf16* qp = &Qb[(bbase + q0 + 16 * half + l16) * DH];
        aq0 = load8(qp + quad * 8);
        aq1 = load8(qp + 32 + quad * 8);
    }

    float4v o[4];
    float m_st[4], l_st[4];
#pragma unroll
    for (int nt = 0; nt < 4; nt++) o[nt] = (float4v)(0.f);
#pragma unroll
    for (int r = 0; r < 4; r++) { m_st[r] = -1e30f; l_st[r] = 0.f; }

    const int rbase  = 16 * half + quad * 4;   // local row 0..31
    const int i_base = q0 + rbase;

    for (int j0 = 64 * strm; j0 < q0 + 32; j0 += 256) {
        // ---- S = Q K^T ----
        float4v s[4];
#pragma unroll
        for (int nt = 0; nt < 4; nt++) s[nt] = (float4v)(0.f);
#pragma unroll
        for (int nt = 0; nt < 4; nt++) {
            const bf16* kp = &Kb[(bbase + j0 + 16 * nt + l16) * DH];
            short8 b0 = load8(kp + quad * 8);
            short8 b1 = load8(kp + 32 + quad * 8);
            s[nt] = __builtin_amdgcn_mfma_f32_16x16x32_bf16(aq0, b0, s[nt], 0, 0, 0);
            s[nt] = __builtin_amdgcn_mfma_f32_16x16x32_bf16(aq1, b1, s[nt], 0, 0, 0);
        }

        // ---- scale + bias + causal mask ----
        float p[4][4];
        float mcur[4];
#pragma unroll
        for (int r = 0; r < 4; r++) mcur[r] = -1e30f;

        if (j0 + 71 <= q0) {          // interior: no mask, bias = rel[0]
#pragma unroll
            for (int nt = 0; nt < 4; nt++)
#pragma unroll
                for (int r = 0; r < 4; r++) {
                    float val = s[nt][r] * 0.125f + rel0;
                    p[nt][r] = val;
                    mcur[r] = fmaxf(mcur[r], val);
                }
        } else {
#pragma unroll
            for (int nt = 0; nt < 4; nt++) {
                const int j = j0 + 16 * nt + l16;
#pragma unroll
                for (int r = 0; r < 4; r++) {
                    const int i = i_base + r;
                    const int d = j - i;
                    int idx = d + 8;
                    idx = idx < 0 ? 0 : (idx > 16 ? 16 : idx);
                    float val = s[nt][r] * 0.125f + s_rel[idx];
                    val = (d > 0) ? -1e30f : val;
                    p[nt][r] = val;
                    mcur[r] = fmaxf(mcur[r], val);
                }
            }
        }

        // ---- row max across 16 lanes ----
#pragma unroll
        for (int m = 1; m < 16; m <<= 1)
#pragma unroll
            for (int r = 0; r < 4; r++)
                mcur[r] = fmaxf(mcur[r], __shfl_xor(mcur[r], m, 64));

        float alpha[4], lsum[4];
#pragma unroll
        for (int r = 0; r < 4; r++) {
            const float mn = fmaxf(m_st[r], mcur[r]);
            alpha[r] = __expf(m_st[r] - mn);
            m_st[r] = mn;
            lsum[r] = 0.f;
        }
#pragma unroll
        for (int nt = 0; nt < 4; nt++)
#pragma unroll
            for (int r = 0; r < 4; r++) {
                const float pv = __expf(p[nt][r] - m_st[r]);
                p[nt][r] = pv;
                lsum[r] += pv;
            }
#pragma unroll
        for (int m = 1; m < 16; m <<= 1)
#pragma unroll
            for (int r = 0; r < 4; r++)
                lsum[r] += __shfl_xor(lsum[r], m, 64);
#pragma unroll
        for (int r = 0; r < 4; r++)
            l_st[r] = l_st[r] * alpha[r] + lsum[r];
#pragma unroll
        for (int nt = 0; nt < 4; nt++)
#pragma unroll
            for (int r = 0; r < 4; r++) o[nt][r] *= alpha[r];

        // ---- P (C-layout) -> per-wave LDS -> A-operand layout ----
#pragma unroll
        for (int nt = 0; nt < 4; nt++)
#pragma unroll
            for (int r = 0; r < 4; r++)
                Pw[(quad * 4 + r) * 72 + 16 * nt + l16] = __float2bfloat16(p[nt][r]);

        short8 ap0 = load8(&Pw[l16 * 72 + quad * 8]);
        short8 ap1 = load8(&Pw[l16 * 72 + 32 + quad * 8]);

        // ---- O += P V ----
#pragma unroll
        for (int nt = 0; nt < 4; nt++) {
            const bf16* vp = &Vt[((size_t)batch * DH + 16 * nt + l16) * TT + j0];
            short8 bv0 = load8(vp + quad * 8);
            short8 bv1 = load8(vp + 32 + quad * 8);
            o[nt] = __builtin_amdgcn_mfma_f32_16x16x32_bf16(ap0, bv0, o[nt], 0, 0, 0);
            o[nt] = __builtin_amdgcn_mfma_f32_16x16x32_bf16(ap1, bv1, o[nt], 0, 0, 0);
        }
    }

    // ---- publish per-stream partials ----
    if (l16 == 0) {
#pragma unroll
        for (int r = 0; r < 4; r++) {
            m_sh[strm][rbase + r] = m_st[r];
            l_sh[strm][rbase + r] = l_st[r];
        }
    }
#pragma unroll
    for (int nt = 0; nt < 4; nt++)
#pragma unroll
        for (int r = 0; r < 4; r++)
            O_sh[strm][rbase + r][16 * nt + l16] = o[nt][r];

    __syncthreads();

    // ---- merge 4 streams (waves with strm==0) ----
    if (strm == 0) {
#pragma unroll
        for (int r = 0; r < 4; r++) {
            const int row = rbase + r;
            float M = m_sh[0][row];
#pragma unroll
            for (int s2 = 1; s2 < 4; s2++) M = fmaxf(M, m_sh[s2][row]);
            float e[4], L = 0.f;
#pragma unroll
            for (int s2 = 0; s2 < 4; s2++) {
                e[s2] = __expf(m_sh[s2][row] - M);
                L += l_sh[s2][row] * e[s2];
            }
            const float rL = 1.0f / L;
#pragma unroll
            for (int nt = 0; nt < 4; nt++) {
                const int c = 16 * nt + l16;
                float acc = 0.f;
#pragma unroll
                for (int s2 = 0; s2 < 4; s2++)
                    acc += O_sh[s2][row][c] * e[s2];
                out[(bbase + q0 + row) * DH + c] = acc * rL;
            }
        }
    }
}

// ---------------------------------------------------------------------------
extern "C" void kernel_launch(void* const* d_in, const int* in_sizes, int n_in,
                              void* d_out, int out_size, void* d_ws, size_t ws_size,
                              hipStream_t stream)
{
    const float* x   = (const float*)d_in[0];
    const float* Wq  = (const float*)d_in[1];
    const float* Wk  = (const float*)d_in[2];
    const float* Wv  = (const float*)d_in[3];
    const float* rel = (const float*)d_in[4];
    float* out = (float*)d_out;

    bf16* Qb = (bf16*)d_ws;                       // [B*T, 64] bf16
    bf16* Kb = Qb + (size_t)BT * TT * DH;         // [B*T, 64] bf16
    bf16* Vt = Kb + (size_t)BT * TT * DH;         // [B, 64, T] bf16
    bf16* Wb = Vt + (size_t)BT * TT * DH;         // [192, 1024] bf16

    w_prep<<<192, 256, 0, stream>>>(Wq, Wk, Wv, Wb);
    qkv_gemm<<<1024, 256, 0, stream>>>(x, Wb, Qb, Kb, Vt);
    attn<<<512, 512, 0, stream>>>(Qb, Kb, Vt, rel, out);
}

// Round 4
// 230.051 us; speedup vs baseline: 1.6048x; 1.1577x over previous
//
#include <hip/hip_runtime.h>
#include <hip/hip_bf16.h>

#define BT 4
#define TT 4096
#define DM 1024
#define DH 64
#define NRE 17   // 2*MAX_REL+1
#define BK 128   // f32 elements of x staged per chunk in qkv_gemm

using bf16 = __hip_bfloat16;
typedef __attribute__((ext_vector_type(8))) short short8;
typedef __attribute__((ext_vector_type(4))) short short4v;
typedef __attribute__((ext_vector_type(4))) float float4v;

static __device__ __forceinline__ short8 load8(const bf16* p) {
    return *reinterpret_cast<const short8*>(p);
}
static __device__ __forceinline__ short bfbits(float x) {
    return (short)__bfloat16_as_ushort(__float2bfloat16(x));
}
// two (possibly non-adjacent) float4s -> 8 bf16 fragment
static __device__ __forceinline__ short8 cvt8_2(const float* p0, const float* p1) {
    float4v a = *reinterpret_cast<const float4v*>(p0);
    float4v b = *reinterpret_cast<const float4v*>(p1);
    short8 r;
    r[0] = bfbits(a[0]); r[1] = bfbits(a[1]); r[2] = bfbits(a[2]); r[3] = bfbits(a[3]);
    r[4] = bfbits(b[0]); r[5] = bfbits(b[1]); r[6] = bfbits(b[2]); r[7] = bfbits(b[3]);
    return r;
}
// async global->LDS, 16B per lane; lds dest must be wave-uniform base
static __device__ __forceinline__ void gload_lds16(const float* g, float* l) {
    __builtin_amdgcn_global_load_lds(
        (const __attribute__((address_space(1))) void*)g,
        (__attribute__((address_space(3))) void*)l, 16, 0, 0);
}

// ---------------------------------------------------------------------------
// Kernel 0: W prep — concat Wq|Wk|Wv (192x1024) f32 -> bf16 once.
// ---------------------------------------------------------------------------
__global__ __launch_bounds__(256) void w_prep(
    const float* __restrict__ Wq, const float* __restrict__ Wk,
    const float* __restrict__ Wv, bf16* __restrict__ Wb)
{
    const int row = blockIdx.x;          // 0..191
    const float* src = (row < 64) ? &Wq[(size_t)row * DM]
                     : (row < 128) ? &Wk[(size_t)(row - 64) * DM]
                                   : &Wv[(size_t)(row - 128) * DM];
    float4v v = reinterpret_cast<const float4v*>(src)[threadIdx.x];
    short4v s;
    s[0] = bfbits(v[0]); s[1] = bfbits(v[1]); s[2] = bfbits(v[2]); s[3] = bfbits(v[3]);
    *reinterpret_cast<short4v*>(&Wb[(size_t)row * DM + 4 * threadIdx.x]) = s;
}

// ---------------------------------------------------------------------------
// Kernel 1: QKV GEMM, x staged via global_load_lds (double-buffered, XOR-
// swizzled so b128 reads are bank-uniform). Block = 32 rows, 8 waves: wave =
// (row-half 16) x (48-col quarter). W bf16 direct (L1/L2).
// ---------------------------------------------------------------------------
__global__ __launch_bounds__(512, 4) void qkv_gemm(
    const float* __restrict__ x, const bf16* __restrict__ Wb,
    bf16* __restrict__ Qb, bf16* __restrict__ Kb, bf16* __restrict__ Vt)
{
    __shared__ float xs[2][32][BK];      // 2 x 16 KB

    const int w     = threadIdx.x >> 6;  // 0..7
    const int lane  = threadIdx.x & 63;
    const int quad  = lane >> 4;
    const int l16   = lane & 15;
    const int half  = w & 1;
    const int colq  = w >> 1;            // 0..3
    const int row0  = blockIdx.x * 32;

    const int srow  = lane >> 5;         // 0/1: row within 2-row segment
    const int punit = lane & 31;         // 16B unit within 512B row

    float4v acc[3];
#pragma unroll
    for (int i = 0; i < 3; i++) acc[i] = (float4v)(0.f);

    const bf16* W48 = Wb + (size_t)(48 * colq) * DM;

    // prologue: stage chunk 0
#pragma unroll
    for (int r2 = 0; r2 < 2; r2++) {
        const int s   = 2 * w + r2;
        const int row = 2 * s + srow;
        const int u   = punit ^ row;     // XOR swizzle (row < 32)
        gload_lds16(&x[(size_t)(row0 + row) * DM + 4 * u], &xs[0][2 * s][0]);
    }
    __syncthreads();

    const int R = 16 * half + l16;       // this lane's x row in the block
    for (int c = 0; c < DM / BK; c++) {
        const int buf = c & 1;
        if (c + 1 < DM / BK) {
#pragma unroll
            for (int r2 = 0; r2 < 2; r2++) {
                const int s   = 2 * w + r2;
                const int row = 2 * s + srow;
                const int u   = punit ^ row;
                gload_lds16(&x[(size_t)(row0 + row) * DM + (c + 1) * BK + 4 * u],
                            &xs[buf ^ 1][2 * s][0]);
            }
        }
#pragma unroll
        for (int ks = 0; ks < BK; ks += 32) {
            const int u0 = (ks >> 2) + 2 * quad;           // multiple-of-8 + 2q
            const float* p0 = &xs[buf][R][4 * (u0 ^ R)];
            const float* p1 = &xs[buf][R][4 * ((u0 + 1) ^ R)];
            short8 a = cvt8_2(p0, p1);
#pragma unroll
            for (int nt = 0; nt < 3; nt++) {
                short8 b = load8(&W48[(size_t)(16 * nt + l16) * DM + c * BK + ks + quad * 8]);
                acc[nt] = __builtin_amdgcn_mfma_f32_16x16x32_bf16(a, b, acc[nt], 0, 0, 0);
            }
        }
        __syncthreads();
    }

#pragma unroll
    for (int nt = 0; nt < 3; nt++) {
        const int cc = 48 * colq + 16 * nt + l16;          // 0..191
#pragma unroll
        for (int r = 0; r < 4; r++) {
            const int i = row0 + 16 * half + quad * 4 + r; // global row b*T+t
            bf16 hv = __float2bfloat16(acc[nt][r]);
            if (cc < 64) {
                Qb[(size_t)i * DH + cc] = hv;
            } else if (cc < 128) {
                Kb[(size_t)i * DH + (cc - 64)] = hv;
            } else {
                const int d  = cc - 128;
                const int b_ = i >> 12;
                const int tt = i & (TT - 1);
                Vt[((size_t)b_ * DH + d) * TT + tt] = hv;
            }
        }
    }
}

// ---------------------------------------------------------------------------
// Kernel 2: flash causal attention, S^T formulation.
// S^T = K Q^T (A=K rows j, B=Q rows i) => q-rows on l16: scalar m/l per lane,
// row-reduce = reg-local + shfl_xor(16,32). P^T regs are directly the
// B-operand of mfma_f32_16x16x16bf16_1k (k = 4*quad + reg), A = Vt rows (d on
// l16): O[d on quad*4+r][i on l16] — no LDS round-trip anywhere.
// Block = 512 thr = 8 waves = 8 KV streams x same 16 q-rows; merge via LDS.
// Grid 1024 = 4 batch x 256 q-tiles(16 rows), big/small paired remap.
// ---------------------------------------------------------------------------
__global__ __launch_bounds__(512, 4) void attn(
    const bf16* __restrict__ Qb, const bf16* __restrict__ Kb,
    const bf16* __restrict__ Vt, const float* __restrict__ rel,
    float* __restrict__ out)
{
    __shared__ float s_rel[NRE];
    __shared__ float m_sh[8][16], l_sh[8][16];
    __shared__ float O_sh[8][16][64];

    const int strm  = threadIdx.x >> 6;  // 0..7: KV stream
    const int lane  = threadIdx.x & 63;
    const int quad  = lane >> 4;
    const int l16   = lane & 15;
    const int batch = blockIdx.x & 3;
    const int b2    = blockIdx.x >> 2;                  // 0..255
    const int t     = (b2 < 128) ? b2 : (383 - b2);     // pair big+small on CU
    const int q0    = t * 16;

    if (threadIdx.x < NRE) s_rel[threadIdx.x] = rel[threadIdx.x];
    __syncthreads();
    const float rel0 = s_rel[0];

    const size_t bbase = (size_t)batch * TT;
    const int i_row = q0 + l16;          // this lane's q row

    // Q B-fragments (n = i on l16), k = quad*8.. for 16x16x32
    short8 bq0, bq1;
    {
        const bf16* qp = &Qb[(bbase + i_row) * DH];
        bq0 = load8(qp + quad * 8);
        bq1 = load8(qp + 32 + quad * 8);
    }

    float4v o[4];                        // o[dt][r]: O[i=l16][d=16dt+4quad+r]
#pragma unroll
    for (int dt = 0; dt < 4; dt++) o[dt] = (float4v)(0.f);
    float m_st = -1e30f, l_st = 0.f;

    for (int j0 = 64 * strm; j0 < q0 + 16; j0 += 512) {
        // ---- S^T = K Q^T : st[nt] rows j=j0+16nt+4quad+r, cols i=l16 ----
        float4v st[4];
#pragma unroll
        for (int nt = 0; nt < 4; nt++) st[nt] = (float4v)(0.f);
#pragma unroll
        for (int nt = 0; nt < 4; nt++) {
            const bf16* kp = &Kb[(bbase + j0 + 16 * nt + l16) * DH];
            short8 a0 = load8(kp + quad * 8);
            short8 a1 = load8(kp + 32 + quad * 8);
            st[nt] = __builtin_amdgcn_mfma_f32_16x16x32_bf16(a0, bq0, st[nt], 0, 0, 0);
            st[nt] = __builtin_amdgcn_mfma_f32_16x16x32_bf16(a1, bq1, st[nt], 0, 0, 0);
        }

        // ---- scale + bias + causal mask ----
        float mcur = -1e30f;
        if (j0 + 71 <= q0) {             // interior: no mask, bias = rel[0]
#pragma unroll
            for (int nt = 0; nt < 4; nt++)
#pragma unroll
                for (int r = 0; r < 4; r++) {
                    float v = st[nt][r] * 0.125f + rel0;
                    st[nt][r] = v;
                    mcur = fmaxf(mcur, v);
                }
        } else {
#pragma unroll
            for (int nt = 0; nt < 4; nt++) {
                const int jb = j0 + 16 * nt + 4 * quad;
#pragma unroll
                for (int r = 0; r < 4; r++) {
                    const int d = jb + r - i_row;
                    int idx = d + 8;
                    idx = idx < 0 ? 0 : (idx > 16 ? 16 : idx);
                    float v = st[nt][r] * 0.125f + s_rel[idx];
                    v = (d > 0) ? -1e30f : v;
                    st[nt][r] = v;
                    mcur = fmaxf(mcur, v);
                }
            }
        }

        // ---- row max: reg-local done above, cross-quad via 2 shfls ----
        mcur = fmaxf(mcur, __shfl_xor(mcur, 16, 64));
        mcur = fmaxf(mcur, __shfl_xor(mcur, 32, 64));

        const float mn = fmaxf(m_st, mcur);
        const float alpha = __expf(m_st - mn);
        m_st = mn;

        float lsum = 0.f;
        short4v pb[4];                   // P^T bf16: B-operand of 16x16x16
#pragma unroll
        for (int nt = 0; nt < 4; nt++)
#pragma unroll
            for (int r = 0; r < 4; r++) {
                const float e = __expf(st[nt][r] - mn);
                lsum += e;
                pb[nt][r] = bfbits(e);
            }
        lsum += __shfl_xor(lsum, 16, 64);
        lsum += __shfl_xor(lsum, 32, 64);
        l_st = l_st * alpha + lsum;

#pragma unroll
        for (int dt = 0; dt < 4; dt++)
#pragma unroll
            for (int r = 0; r < 4; r++) o[dt][r] *= alpha;

        // ---- O += V^T P : A = Vt rows (d=16dt+l16, k=j0+16nt+4quad+jj) ----
#pragma unroll
        for (int nt = 0; nt < 4; nt++) {
#pragma unroll
            for (int dt = 0; dt < 4; dt++) {
                const bf16* vp = &Vt[((size_t)batch * DH + 16 * dt + l16) * TT
                                     + j0 + 16 * nt + 4 * quad];
                short4v va = *reinterpret_cast<const short4v*>(vp);
                o[dt] = __builtin_amdgcn_mfma_f32_16x16x16bf16_1k(va, pb[nt], o[dt], 0, 0, 0);
            }
        }
    }

    // ---- publish per-stream partials ----
    if (quad == 0) {
        m_sh[strm][l16] = m_st;
        l_sh[strm][l16] = l_st;
    }
#pragma unroll
    for (int dt = 0; dt < 4; dt++)
        *reinterpret_cast<float4v*>(&O_sh[strm][l16][16 * dt + 4 * quad]) = o[dt];

    __syncthreads();

    // ---- merge 8 streams: 16 rows x 64 cols, 512 threads -> 2 each ----
    for (int idx = threadIdx.x; idx < 16 * 64; idx += 512) {
        const int row = idx >> 6;
        const int c   = idx & 63;
        float M = m_sh[0][row];
#pragma unroll
        for (int s2 = 1; s2 < 8; s2++) M = fmaxf(M, m_sh[s2][row]);
        float L = 0.f, acc = 0.f;
#pragma unroll
        for (int s2 = 0; s2 < 8; s2++) {
            const float e = __expf(m_sh[s2][row] - M);
            L   += l_sh[s2][row] * e;
            acc += O_sh[s2][row][c] * e;
        }
        out[(bbase + q0 + row) * DH + c] = acc / L;
    }
}

// ---------------------------------------------------------------------------
extern "C" void kernel_launch(void* const* d_in, const int* in_sizes, int n_in,
                              void* d_out, int out_size, void* d_ws, size_t ws_size,
                              hipStream_t stream)
{
    const float* x   = (const float*)d_in[0];
    const float* Wq  = (const float*)d_in[1];
    const float* Wk  = (const float*)d_in[2];
    const float* Wv  = (const float*)d_in[3];
    const float* rel = (const float*)d_in[4];
    float* out = (float*)d_out;

    bf16* Qb = (bf16*)d_ws;                       // [B*T, 64] bf16
    bf16* Kb = Qb + (size_t)BT * TT * DH;         // [B*T, 64] bf16
    bf16* Vt = Kb + (size_t)BT * TT * DH;         // [B, 64, T] bf16
    bf16* Wb = Vt + (size_t)BT * TT * DH;         // [192, 1024] bf16

    w_prep<<<192, 256, 0, stream>>>(Wq, Wk, Wv, Wb);
    qkv_gemm<<<512, 512, 0, stream>>>(x, Wb, Qb, Kb, Vt);
    attn<<<1024, 512, 0, stream>>>(Qb, Kb, Vt, rel, out);
}